// Round 19
// baseline (111.652 us; speedup 1.0000x reference)
//
#include <hip/hip_runtime.h>
#include <hip/hip_fp16.h>
#include <math.h>

#define T_TOKENS 16384
#define D_DIM    2048
#define NEXP     256
#define TOPK     8
#define NLIM     4
#define BM       16          // block: 16 tokens; grid 1024 -> 4 blocks/CU
#define NSS      16          // supersteps, BK=128 each (4 sub-k of 32)
#define NTHREADS 512         // 8 waves; wave = 16 tok x 32 exp

typedef __attribute__((ext_vector_type(8))) _Float16 f16x8;  // 4 VGPRs
typedef __attribute__((ext_vector_type(4))) float f32x4;     // MFMA acc

// LDS: A = fp16 x-fragments, 2-ring dbuf (4 KB/ring); Sc aliases after GEMM.
//  A[ring][ks(4)][lane(64)][j(8 fp16)] : fragment-linear, 16B granules
struct GemmBufs { unsigned short A[2][4][64][8]; };     // 8 KB
union SMem {
  GemmBufs g;
  float Sc[BM][260];                                    // 16.6 KB
};

// ---- pre-pass: w[256][2048] f32 -> fp16 in MFMA-fragment order ----
// wf layout (fp16): [kc(64)][nfg(16)][lane(64)][j(8)]
// value = (half) w[ e = nfg*16 + (lane&15) ][ k = kc*32 + (lane>>4)*8 + j ]
__global__ __launch_bounds__(256) void prep_w(const float* __restrict__ w,
                                              unsigned short* __restrict__ wf) {
  const int g   = blockIdx.x * 256 + threadIdx.x;  // 0..65535
  const int kc  = g >> 10;
  const int rem = g & 1023;
  const int nfg = rem >> 6;
  const int l   = rem & 63;
  const int e   = nfg * 16 + (l & 15);
  const int kb  = kc * 32 + ((l >> 4) << 3);
  const float* src = &w[(size_t)e * D_DIM + kb];
  float f[8];
  *reinterpret_cast<float4*>(&f[0]) = *reinterpret_cast<const float4*>(src);
  *reinterpret_cast<float4*>(&f[4]) = *reinterpret_cast<const float4*>(src + 4);
  union { unsigned short s[8]; float4 v; } h;
  #pragma unroll
  for (int j = 0; j < 8; ++j) h.s[j] = __half_as_ushort(__float2half(f[j]));
  *reinterpret_cast<float4*>(wf + (size_t)kc * 8192 + nfg * 512 + l * 8) = h.v;
}

__device__ __forceinline__ unsigned cvt2(float a, float b) {  // RNE pair
  return (unsigned)__half_as_ushort(__float2half(a)) |
         ((unsigned)__half_as_ushort(__float2half(b)) << 16);
}

// ---- one superstep ----
// (1) issue x(n+2)->xn ; (2) B(n)->regs ; (3) ds_read A(n) frags + 8 MFMA ;
// (4) cvt x(n+1) (in xc) -> ds_write ring n^1 ; (5) lgkmcnt(0) + barrier.
__device__ __forceinline__ void body(
    int n, const float* asrc, const unsigned short* wfB,
    int ksw, int lnw, int jhw, int lane,
    float4& xc,    // holds x(n+1)
    float4& xn,    // receives x(n+2)
    SMem& sm, f32x4 (&acc)[2]) {
  // (1) prefetch x(n+2): one full superstep of flight
  if (n + 2 < NSS)
    xn = *reinterpret_cast<const float4*>(asrc + (size_t)(n + 2) * 128);
  __builtin_amdgcn_sched_barrier(0);
  // (2) B(n): 8 dwordx4 into regs (wave-private, L2-hot)
  f16x8 b[2][4];
  #pragma unroll
  for (int nf = 0; nf < 2; ++nf)
    #pragma unroll
    for (int ks = 0; ks < 4; ++ks)
      b[nf][ks] = *reinterpret_cast<const f16x8*>(
          wfB + (size_t)(n * 4 + ks) * 8192 + nf * 512);
  // (3) A(n) frags from LDS (fp16, direct) + MFMA
  const int ring = n & 1;
  f16x8 a[4];
  #pragma unroll
  for (int ks = 0; ks < 4; ++ks)
    a[ks] = *reinterpret_cast<const f16x8*>(&sm.g.A[ring][ks][lane][0]);
  #pragma unroll
  for (int ks = 0; ks < 4; ++ks) {
    acc[0] = __builtin_amdgcn_mfma_f32_16x16x32_f16(a[ks], b[0][ks], acc[0], 0, 0, 0);
    acc[1] = __builtin_amdgcn_mfma_f32_16x16x32_f16(a[ks], b[1][ks], acc[1], 0, 0, 0);
  }
  __builtin_amdgcn_sched_barrier(0);
  // (4) stage x(n+1) -> ring^1 (8B/thread, linear: conflict-free)
  if (n + 1 < NSS) {
    uint2 p;
    p.x = cvt2(xc.x, xc.y);
    p.y = cvt2(xc.z, xc.w);
    *reinterpret_cast<uint2*>(&sm.g.A[ring ^ 1][ksw][lnw][jhw * 4]) = p;
  }
  // (5) LDS-only barrier (x prefetch stays in flight)
  asm volatile("s_waitcnt lgkmcnt(0)" ::: "memory");
  __builtin_amdgcn_sched_barrier(0);
  __builtin_amdgcn_s_barrier();
  __builtin_amdgcn_sched_barrier(0);
}

// ---- fused GEMM (fp16 MFMA; A reg->cvt->ds_write dbuf; B in regs) ----
__global__ __launch_bounds__(NTHREADS, 4) void gate_kernel(
    const float* __restrict__ x,
    const unsigned short* __restrict__ wf,
    const float* __restrict__ bias,
    float* __restrict__ out_w,
    float* __restrict__ out_idx,
    float* __restrict__ out_load) {

  __shared__ SMem sm;
  __shared__ int hist[NEXP];

  const int tid  = threadIdx.x;
  const int row0 = blockIdx.x * BM;
  const int lane = tid & 63;
  const int wid  = tid >> 6;   // 0..7 ; wave owns experts wid*32..wid*32+31

  for (int i = tid; i < NEXP; i += NTHREADS) hist[i] = 0;

  // A staging map: thread owns 8B half-fragment [ksw][lnw][jhw]
  // source: 16B contiguous = x[row0+(lnw&15)][ksw*32+(lnw>>4)*8+jhw*4 .. +3]
  const int ksw = tid >> 7;          // 0..3
  const int lnw = (tid >> 1) & 63;   // 0..63
  const int jhw = tid & 1;           // 0..1
  const float* asrc = &x[(size_t)(row0 + (lnw & 15)) * D_DIM +
                         ksw * 32 + ((lnw >> 4) << 3) + jhw * 4];
  // B source base (fragment-linear wf)
  const unsigned short* wfB = wf + (size_t)(wid * 2) * 512 + (size_t)lane * 8;

  f32x4 acc[2];
  acc[0] = (f32x4)(0.0f);
  acc[1] = (f32x4)(0.0f);

  // ---- prologue: stage superstep 0 into ring 0; prefetch x(1)
  float4 xA, xB;
  {
    float4 p0 = *reinterpret_cast<const float4*>(asrc);
    xA = *reinterpret_cast<const float4*>(asrc + 128);   // x(1)
    uint2 p;
    p.x = cvt2(p0.x, p0.y);
    p.y = cvt2(p0.z, p0.w);
    *reinterpret_cast<uint2*>(&sm.g.A[0][ksw][lnw][jhw * 4]) = p;
  }
  asm volatile("s_waitcnt lgkmcnt(0)" ::: "memory");
  __builtin_amdgcn_sched_barrier(0);
  __builtin_amdgcn_s_barrier();
  __builtin_amdgcn_sched_barrier(0);

  // ---- 16 supersteps (unroll 2 for x ping-pong static names)
  for (int n = 0; n < NSS; n += 2) {
    body(n,     asrc, wfB, ksw, lnw, jhw, lane, xA, xB, sm, acc);
    body(n + 1, asrc, wfB, ksw, lnw, jhw, lane, xB, xA, sm, acc);
  }
  __syncthreads();   // full drain; safe to alias Sc over A

  // ---- epilogue: logits -> Sc (C/D layout: col=lane&15, row=(lane>>4)*4+r)
  #pragma unroll
  for (int nf = 0; nf < 2; ++nf)
    #pragma unroll
    for (int r = 0; r < 4; ++r) {
      const int row = ((lane >> 4) << 2) + r;
      const int col = wid * 32 + nf * 16 + (lane & 15);
      sm.Sc[row][col] = acc[nf][r];
    }
  __syncthreads();

  // ---- routing: one wave per token, lane holds experts 4l..4l+3
  const float4 bsl = *reinterpret_cast<const float4*>(&bias[lane * 4]);
  const int g = lane >> 3;   // group of this lane's experts

  for (int m = wid; m < BM; m += 8) {
    float v[4];
    *reinterpret_cast<float4*>(v) =
        *reinterpret_cast<const float4*>(&sm.Sc[m][lane * 4]);

    // softmax (match jax: subtract row max, exp, divide by sum)
    float mx = fmaxf(fmaxf(v[0], v[1]), fmaxf(v[2], v[3]));
    #pragma unroll
    for (int s = 1; s < 64; s <<= 1) mx = fmaxf(mx, __shfl_xor(mx, s));
    float ex[4], sum = 0.f;
    #pragma unroll
    for (int j = 0; j < 4; ++j) { ex[j] = expf(v[j] - mx); sum += ex[j]; }
    #pragma unroll
    for (int s = 1; s < 64; s <<= 1) sum += __shfl_xor(sum, s);
    float sc[4], sel[4];
    sc[0] = ex[0] / sum; sc[1] = ex[1] / sum;
    sc[2] = ex[2] / sum; sc[3] = ex[3] / sum;
    sel[0] = sc[0] + bsl.x; sel[1] = sc[1] + bsl.y;
    sel[2] = sc[2] + bsl.z; sel[3] = sc[3] + bsl.w;

    // keep original scores for the gather
    *reinterpret_cast<float4*>(&sm.Sc[m][lane * 4]) =
        make_float4(sc[0], sc[1], sc[2], sc[3]);

    // group max (groups of 32 experts = 8 lanes)
    float gv = fmaxf(fmaxf(sel[0], sel[1]), fmaxf(sel[2], sel[3]));
    gv = fmaxf(gv, __shfl_xor(gv, 1));
    gv = fmaxf(gv, __shfl_xor(gv, 2));
    gv = fmaxf(gv, __shfl_xor(gv, 4));

    // top-4 groups, tie -> lower group index (jax.lax.top_k stability)
    unsigned gmask = 0;
    float gcur = gv;
    #pragma unroll
    for (int it = 0; it < NLIM; ++it) {
      float bv2 = gcur; int bi = g;
      #pragma unroll
      for (int s = 1; s < 64; s <<= 1) {
        float ov = __shfl_xor(bv2, s);
        int   oi = __shfl_xor(bi, s);
        if (ov > bv2 || (ov == bv2 && oi < bi)) { bv2 = ov; bi = oi; }
      }
      gmask |= 1u << bi;
      if (g == bi) gcur = -INFINITY;
    }
    if (!((gmask >> g) & 1u)) {
      sel[0] = sel[1] = sel[2] = sel[3] = -INFINITY;
    }

    // top-8 experts, tie -> lower expert index
    const int gtok = row0 + m;
    #pragma unroll
    for (int it = 0; it < TOPK; ++it) {
      float bv2 = sel[0]; int bi = lane * 4;
      #pragma unroll
      for (int j = 1; j < 4; ++j)
        if (sel[j] > bv2) { bv2 = sel[j]; bi = lane * 4 + j; }
      #pragma unroll
      for (int s = 1; s < 64; s <<= 1) {
        float ov = __shfl_xor(bv2, s);
        int   oi = __shfl_xor(bi, s);
        if (ov > bv2 || (ov == bv2 && oi < bi)) { bv2 = ov; bi = oi; }
      }
      if (lane == 0) {
        out_w[(size_t)gtok * TOPK + it]   = sm.Sc[m][bi] * 2.5f;
        out_idx[(size_t)gtok * TOPK + it] = (float)bi;
        atomicAdd(&hist[bi], 1);
      }
      if ((bi >> 2) == lane) sel[bi & 3] = -INFINITY;
    }
  }

  __syncthreads();
  for (int b = tid; b < NEXP; b += NTHREADS)
    if (hist[b]) atomicAdd(&out_load[b], (float)hist[b]);
}

extern "C" void kernel_launch(void* const* d_in, const int* in_sizes, int n_in,
                              void* d_out, int out_size, void* d_ws, size_t ws_size,
                              hipStream_t stream) {
  const float* x    = (const float*)d_in[0];
  const float* w    = (const float*)d_in[1];
  const float* bias = (const float*)d_in[2];
  float* out_w    = (float*)d_out;
  float* out_idx  = out_w + (size_t)T_TOKENS * TOPK;
  float* out_load = out_idx + (size_t)T_TOKENS * TOPK;
  unsigned short* wfrag = (unsigned short*)d_ws;   // 1 MB fragment-ordered fp16 w

  (void)hipMemsetAsync(out_load, 0, NEXP * sizeof(float), stream);
  prep_w<<<256, 256, 0, stream>>>(w, wfrag);
  gate_kernel<<<T_TOKENS / BM, NTHREADS, 0, stream>>>(
      x, wfrag, bias, out_w, out_idx, out_load);
}

// Round 20
// 87.072 us; speedup vs baseline: 1.2823x; 1.2823x over previous
//
#include <hip/hip_runtime.h>
#include <hip/hip_fp16.h>
#include <math.h>

#define T_TOKENS 16384
#define D_DIM    2048
#define NEXP     256
#define TOPK     8
#define NLIM     4
#define BM       32
#define NSS      16          // supersteps, BK=128 each (4 sub-k of 32)
#define NTHREADS 512

typedef __attribute__((ext_vector_type(8))) _Float16 f16x8;  // 4 VGPRs
typedef __attribute__((ext_vector_type(4))) float f32x4;     // MFMA acc

// LDS: A = fp16 x-fragments, 2-ring dbuf (8 KB/ring); Sc aliases after GEMM.
struct GemmBufs { unsigned short A[2][4][2][64][8]; };  // 16 KB
union SMem {
  GemmBufs g;
  float Sc[BM][260];                                    // 33.3 KB
};

// ---- pre-pass: w[256][2048] f32 -> fp16 in MFMA-fragment order ----
// wf layout (fp16): [kc(64)][nfg(16)][lane(64)][j(8)]
// value = (half) w[ e = nfg*16 + (lane&15) ][ k = kc*32 + (lane>>4)*8 + j ]
__global__ __launch_bounds__(256) void prep_w(const float* __restrict__ w,
                                              unsigned short* __restrict__ wf) {
  const int g   = blockIdx.x * 256 + threadIdx.x;  // 0..65535
  const int kc  = g >> 10;
  const int rem = g & 1023;
  const int nfg = rem >> 6;
  const int l   = rem & 63;
  const int e   = nfg * 16 + (l & 15);
  const int kb  = kc * 32 + ((l >> 4) << 3);
  const float* src = &w[(size_t)e * D_DIM + kb];
  float f[8];
  *reinterpret_cast<float4*>(&f[0]) = *reinterpret_cast<const float4*>(src);
  *reinterpret_cast<float4*>(&f[4]) = *reinterpret_cast<const float4*>(src + 4);
  union { unsigned short s[8]; float4 v; } h;
  #pragma unroll
  for (int j = 0; j < 8; ++j) h.s[j] = __half_as_ushort(__float2half(f[j]));
  *reinterpret_cast<float4*>(wf + (size_t)kc * 8192 + nfg * 512 + l * 8) = h.v;
}

__device__ __forceinline__ unsigned cvt2(float a, float b) {  // RNE pair
  return (unsigned)__half_as_ushort(__float2half(a)) |
         ((unsigned)__half_as_ushort(__float2half(b)) << 16);
}
__device__ __forceinline__ uint4 pack8(const float4& lo, const float4& hi) {
  uint4 p;
  p.x = cvt2(lo.x, lo.y); p.y = cvt2(lo.z, lo.w);
  p.z = cvt2(hi.x, hi.y); p.w = cvt2(hi.z, hi.w);
  return p;
}

__device__ __forceinline__ void loadB(f16x8 (&b)[2][4], int n,
                                      const unsigned short* wfB) {
  #pragma unroll
  for (int nf = 0; nf < 2; ++nf)
    #pragma unroll
    for (int ks = 0; ks < 4; ++ks)
      b[nf][ks] = *reinterpret_cast<const f16x8*>(
          wfB + (size_t)(n * 4 + ks) * 8192 + nf * 512);
}

// ---- one superstep ----
// (1) x(n+2)->xn ; (2) B(n+1)->bn ring ; (3) ds_read A(n) + MFMA with bc ;
// (4) cvt x(n+1)->ds_write ring n^1 ; (5) lgkmcnt(0)+barrier (VMEM flies on).
__device__ __forceinline__ void body(
    int n, const float* asrc, const unsigned short* wfB,
    int ksw, int mfw, int lnw, int lane,
    float4& xc0, float4& xc1,    // holds x(n+1)
    float4& xn0, float4& xn1,    // receives x(n+2)
    f16x8 (&bc)[2][4],           // B(n), loaded last superstep
    f16x8 (&bn)[2][4],           // receives B(n+1)
    SMem& sm, f32x4 (&acc)[2][2]) {
  if (n + 2 < NSS) {
    const float* s = asrc + (size_t)(n + 2) * 128;
    xn0 = *reinterpret_cast<const float4*>(s);
    xn1 = *reinterpret_cast<const float4*>(s + 4);
  }
  if (n + 1 < NSS) loadB(bn, n + 1, wfB);
  __builtin_amdgcn_sched_barrier(0);
  // compute step n from LDS ring + bc
  const int ring = n & 1;
  #pragma unroll
  for (int ks = 0; ks < 4; ++ks) {
    f16x8 a0 = *reinterpret_cast<const f16x8*>(&sm.g.A[ring][ks][0][lane][0]);
    f16x8 a1 = *reinterpret_cast<const f16x8*>(&sm.g.A[ring][ks][1][lane][0]);
    acc[0][0] = __builtin_amdgcn_mfma_f32_16x16x32_f16(a0, bc[0][ks], acc[0][0], 0, 0, 0);
    acc[0][1] = __builtin_amdgcn_mfma_f32_16x16x32_f16(a0, bc[1][ks], acc[0][1], 0, 0, 0);
    acc[1][0] = __builtin_amdgcn_mfma_f32_16x16x32_f16(a1, bc[0][ks], acc[1][0], 0, 0, 0);
    acc[1][1] = __builtin_amdgcn_mfma_f32_16x16x32_f16(a1, bc[1][ks], acc[1][1], 0, 0, 0);
  }
  __builtin_amdgcn_sched_barrier(0);
  if (n + 1 < NSS) {
    uint4 p = pack8(xc0, xc1);
    *reinterpret_cast<uint4*>(&sm.g.A[ring ^ 1][ksw][mfw][lnw][0]) = p;
  }
  asm volatile("s_waitcnt lgkmcnt(0)" ::: "memory");
  __builtin_amdgcn_sched_barrier(0);
  __builtin_amdgcn_s_barrier();
  __builtin_amdgcn_sched_barrier(0);
}

// ---- fused GEMM (fp16 MFMA; A dbuf LDS; B register prefetch ring) ----
__global__ __launch_bounds__(NTHREADS, 4) void gate_kernel(
    const float* __restrict__ x,
    const unsigned short* __restrict__ wf,
    const float* __restrict__ bias,
    float* __restrict__ out_w,
    float* __restrict__ out_idx,
    float* __restrict__ out_load) {

  __shared__ SMem sm;
  __shared__ int hist[NEXP];

  const int tid  = threadIdx.x;
  const int row0 = blockIdx.x * BM;
  const int lane = tid & 63;
  const int wid  = tid >> 6;   // 0..7

  for (int i = tid; i < NEXP; i += NTHREADS) hist[i] = 0;

  // A staging map (16B/thread, linear, conflict-free; coalesced 32B source)
  const int ksw = tid >> 7;
  const int mfw = (tid >> 6) & 1;
  const int lnw = tid & 63;
  const float* asrc = &x[(size_t)(row0 + mfw * 16 + (lnw & 15)) * D_DIM +
                         ksw * 32 + ((lnw >> 4) << 3)];
  const unsigned short* wfB = wf + (size_t)(wid * 2) * 512 + (size_t)lane * 8;

  f32x4 acc[2][2];
  #pragma unroll
  for (int i = 0; i < 2; ++i)
    #pragma unroll
    for (int j = 0; j < 2; ++j) acc[i][j] = (f32x4)(0.0f);

  // ---- prologue: stage step 0; prefetch x(1); load B(0)
  float4 xA0, xA1, xB0, xB1;
  f16x8 bA[2][4], bB[2][4];
  {
    float4 p0 = *reinterpret_cast<const float4*>(asrc);
    float4 p1 = *reinterpret_cast<const float4*>(asrc + 4);
    xA0 = *reinterpret_cast<const float4*>(asrc + 128);   // x(1)
    xA1 = *reinterpret_cast<const float4*>(asrc + 132);
    loadB(bA, 0, wfB);
    uint4 p = pack8(p0, p1);
    *reinterpret_cast<uint4*>(&sm.g.A[0][ksw][mfw][lnw][0]) = p;
  }
  asm volatile("s_waitcnt lgkmcnt(0)" ::: "memory");
  __builtin_amdgcn_sched_barrier(0);
  __builtin_amdgcn_s_barrier();
  __builtin_amdgcn_sched_barrier(0);

  // ---- 16 supersteps (unroll 2: static ping-pong names for x and B rings)
  for (int n = 0; n < NSS; n += 2) {
    body(n,     asrc, wfB, ksw, mfw, lnw, lane, xA0, xA1, xB0, xB1, bA, bB, sm, acc);
    body(n + 1, asrc, wfB, ksw, mfw, lnw, lane, xB0, xB1, xA0, xA1, bB, bA, sm, acc);
  }
  __syncthreads();   // drain; safe to alias Sc over A

  // ---- epilogue: logits -> Sc (C/D: col=lane&15, row=(lane>>4)*4+r)
  #pragma unroll
  for (int mf = 0; mf < 2; ++mf)
    #pragma unroll
    for (int nf = 0; nf < 2; ++nf)
      #pragma unroll
      for (int r = 0; r < 4; ++r) {
        const int row = mf * 16 + ((lane >> 4) << 2) + r;
        const int col = wid * 32 + nf * 16 + (lane & 15);
        sm.Sc[row][col] = acc[mf][nf][r];
      }
  __syncthreads();

  // ---- routing: lane-group-of-8. Wave handles 8 tokens; lane owns one
  // 32-expert group (register-resident). Shuffles only across 8 lanes.
  if (wid < 4) {
    const int t8  = lane >> 3;           // token within wave
    const int g2  = lane & 7;            // expert group of this lane
    const int tokl = wid * 8 + t8;       // 0..31
    const int gtok = row0 + tokl;

    // rotated chunk read: c=(jc+g2)&7 -> per-8-lane phase hits 8 distinct
    // 4-bank groups (conflict-free). slot jc*4+e holds expert g2*32+c*4+e.
    float sc[32], sel[32];
    #pragma unroll
    for (int jc = 0; jc < 8; ++jc) {
      const int c = (jc + g2) & 7;
      float4 v = *reinterpret_cast<const float4*>(&sm.Sc[tokl][g2 * 32 + c * 4]);
      sc[jc * 4 + 0] = v.x; sc[jc * 4 + 1] = v.y;
      sc[jc * 4 + 2] = v.z; sc[jc * 4 + 3] = v.w;
    }
    // softmax over all 256 (serial 32 + 3-stage shuffle across 8 lanes)
    float mx = sc[0];
    #pragma unroll
    for (int s = 1; s < 32; ++s) mx = fmaxf(mx, sc[s]);
    mx = fmaxf(mx, __shfl_xor(mx, 1));
    mx = fmaxf(mx, __shfl_xor(mx, 2));
    mx = fmaxf(mx, __shfl_xor(mx, 4));
    float sum = 0.f;
    #pragma unroll
    for (int s = 0; s < 32; ++s) { sc[s] = expf(sc[s] - mx); sum += sc[s]; }
    sum += __shfl_xor(sum, 1);
    sum += __shfl_xor(sum, 2);
    sum += __shfl_xor(sum, 4);
    #pragma unroll
    for (int s = 0; s < 32; ++s) sc[s] = sc[s] / sum;
    // sel = sc + bias (same rotated order)
    #pragma unroll
    for (int jc = 0; jc < 8; ++jc) {
      const int c = (jc + g2) & 7;
      float4 b4 = *reinterpret_cast<const float4*>(&bias[g2 * 32 + c * 4]);
      sel[jc * 4 + 0] = sc[jc * 4 + 0] + b4.x;
      sel[jc * 4 + 1] = sc[jc * 4 + 1] + b4.y;
      sel[jc * 4 + 2] = sc[jc * 4 + 2] + b4.z;
      sel[jc * 4 + 3] = sc[jc * 4 + 3] + b4.w;
    }
    // group top-4 (this lane IS group g2), tie -> lower group
    float gv = sel[0];
    #pragma unroll
    for (int s = 1; s < 32; ++s) gv = fmaxf(gv, sel[s]);
    float gcur = gv;
    int kept = 0;
    #pragma unroll
    for (int it = 0; it < NLIM; ++it) {
      float bv = gcur; int bl = g2;
      #pragma unroll
      for (int s = 1; s < 8; s <<= 1) {
        float ov = __shfl_xor(bv, s);
        int   ol = __shfl_xor(bl, s);
        if (ov > bv || (ov == bv && ol < bl)) { bv = ov; bl = ol; }
      }
      if (g2 == bl) { kept = 1; gcur = -INFINITY; }
    }
    if (!kept) {
      #pragma unroll
      for (int s = 0; s < 32; ++s) sel[s] = -INFINITY;
    }
    // top-8 experts, tie -> lower expert index
    #pragma unroll
    for (int it = 0; it < TOPK; ++it) {
      float lv = -INFINITY; int lei = 0x7FFFFFFF, lslot = -1;
      #pragma unroll
      for (int s = 0; s < 32; ++s) {
        const int eidx = g2 * 32 + (((s >> 2) + g2) & 7) * 4 + (s & 3);
        if (sel[s] > lv || (sel[s] == lv && eidx < lei)) {
          lv = sel[s]; lei = eidx; lslot = s;
        }
      }
      float bv = lv; int bei = lei;
      #pragma unroll
      for (int s = 1; s < 8; s <<= 1) {
        float ov = __shfl_xor(bv, s);
        int   oe = __shfl_xor(bei, s);
        if (ov > bv || (ov == bv && oe < bei)) { bv = ov; bei = oe; }
      }
      const bool win = ((bei >> 5) == g2);
      if (win) {
        float wv = 0.f;
        #pragma unroll
        for (int s = 0; s < 32; ++s) if (s == lslot) wv = sc[s];
        out_w[(size_t)gtok * TOPK + it]   = wv * 2.5f;
        out_idx[(size_t)gtok * TOPK + it] = (float)bei;
        atomicAdd(&hist[bei], 1);
      }
      #pragma unroll
      for (int s = 0; s < 32; ++s)
        if (win && s == lslot) sel[s] = -INFINITY;
    }
  }

  __syncthreads();
  for (int b = tid; b < NEXP; b += NTHREADS)
    if (hist[b]) atomicAdd(&out_load[b], (float)hist[b]);
}

extern "C" void kernel_launch(void* const* d_in, const int* in_sizes, int n_in,
                              void* d_out, int out_size, void* d_ws, size_t ws_size,
                              hipStream_t stream) {
  const float* x    = (const float*)d_in[0];
  const float* w    = (const float*)d_in[1];
  const float* bias = (const float*)d_in[2];
  float* out_w    = (float*)d_out;
  float* out_idx  = out_w + (size_t)T_TOKENS * TOPK;
  float* out_load = out_idx + (size_t)T_TOKENS * TOPK;
  unsigned short* wfrag = (unsigned short*)d_ws;   // 1 MB fragment-ordered fp16 w

  (void)hipMemsetAsync(out_load, 0, NEXP * sizeof(float), stream);
  prep_w<<<256, 256, 0, stream>>>(w, wfrag);
  gate_kernel<<<T_TOKENS / BM, NTHREADS, 0, stream>>>(
      x, wfrag, bias, out_w, out_idx, out_load);
}